// Round 7
// baseline (553.109 us; speedup 1.0000x reference)
//
#include <hip/hip_runtime.h>
#include <hip/hip_cooperative_groups.h>
#include <math.h>

namespace cg = cooperative_groups;

#define NDIM 64
#define LRELU_SLOPE 0.2f
#define BSHIFT 8               // 256 nodes per bucket
#define BNODES 256
#define ECAP 3584              // edge capacity per bucket (mean 2558, ~20 sigma headroom)
#define CCAP (ECAP + BNODES)   // csr capacity per bucket (edges + self loops)

typedef float f32x2 __attribute__((ext_vector_type(2)));

__device__ __forceinline__ ushort f2bf(float f) {
    unsigned u = __float_as_uint(f);
    unsigned r = (u + 0x7fffu + ((u >> 16) & 1u)) >> 16;   // RTNE
    return (ushort)r;
}
__device__ __forceinline__ float bflo(unsigned u) { return __uint_as_float(u << 16); }
__device__ __forceinline__ float bfhi(unsigned u) { return __uint_as_float(u & 0xffff0000u); }

// ---- LDS arena (overlaid per phase; max user = gemm 16K+4.35K+2K) ----
#define SMEM_BYTES 22784

// ---------------- partition unit (one 4096-edge chunk) ---------------------
__device__ __forceinline__ void part_unit(
    unsigned char* SMEM, int unit,
    const int* __restrict__ src, const int* __restrict__ dst,
    int* __restrict__ bcur, unsigned* __restrict__ part, int E, int nb) {
    int* hist = (int*)SMEM;              // 512 ints
    int* base = (int*)(SMEM + 2048);     // 512 ints
    int t = threadIdx.x;
    for (int i = t; i < nb; i += 256) hist[i] = 0;
    __syncthreads();
    int chunk = unit * 4096;
    int s[16], d[16];
#pragma unroll
    for (int j = 0; j < 4; ++j) {
        int idx = chunk + j * 1024 + t * 4;
        if (idx + 3 < E) {
            int4 sv = *(const int4*)(src + idx);
            int4 dv = *(const int4*)(dst + idx);
            s[j*4+0]=sv.x; s[j*4+1]=sv.y; s[j*4+2]=sv.z; s[j*4+3]=sv.w;
            d[j*4+0]=dv.x; d[j*4+1]=dv.y; d[j*4+2]=dv.z; d[j*4+3]=dv.w;
        } else {
#pragma unroll
            for (int q = 0; q < 4; ++q) {
                int i2 = idx + q;
                if (i2 < E) { s[j*4+q] = src[i2]; d[j*4+q] = dst[i2]; }
                else        { s[j*4+q] = 0;       d[j*4+q] = -1; }
            }
        }
    }
#pragma unroll
    for (int j = 0; j < 16; ++j)
        if (d[j] >= 0) atomicAdd(&hist[d[j] >> BSHIFT], 1);
    __syncthreads();
    for (int i = t; i < nb; i += 256) {
        int c = hist[i];
        base[i] = c ? atomicAdd(&bcur[i], c) : 0;
        hist[i] = 0;          // reuse as running cursor
    }
    __syncthreads();
#pragma unroll
    for (int j = 0; j < 16; ++j) {
        if (d[j] >= 0) {
            int b = d[j] >> BSHIFT;
            int pos = base[b] + atomicAdd(&hist[b], 1);
            int lim = (b + 1) * ECAP - 1;
            if (pos > lim) pos = lim;   // never fires statistically; memory safety
            part[pos] = ((unsigned)(d[j] & (BNODES - 1)) << 17) | (unsigned)s[j];
        }
    }
}

// ---------------- j-split GEMM unit (64 nodes) -----------------------------
template<int K, int KS, bool BF16IN>
__device__ __forceinline__ void gemm_unit(
    unsigned char* SMEM, int base,
    const void* __restrict__ Xv, const float* __restrict__ W,
    const float* __restrict__ asrc, const float* __restrict__ adst,
    unsigned char* __restrict__ h, float* __restrict__ as_,
    float* __restrict__ ad_, int N) {
    float* xs = (float*)SMEM;                         // 64*KS floats
    unsigned* hsq = (unsigned*)(SMEM + 16384);        // 64*17 u32
    auto ps = (float(*)[4][64])(SMEM + 20736);        // [2][4][64]
    int t = threadIdx.x;
    if (BF16IN) {
        const unsigned* X = (const unsigned*)Xv;   // K/2 uints per row
        for (int i = t; i < 64 * (K / 2); i += 256) {
            int nl = i / (K / 2), p = i - nl * (K / 2);
            int k = p * 2;
            int node = base + nl;
            unsigned u = (node < N) ? X[(size_t)node * (K / 2) + p] : 0u;
            xs[nl * KS + ((k + nl) & (KS - 1))] = bflo(u);
            xs[nl * KS + ((k + 1 + nl) & (KS - 1))] = bfhi(u);
        }
    } else {
        const float* X = (const float*)Xv;
        for (int i = t; i < 64 * KS; i += 256) {
            int nl = i / KS, k = i - nl * KS;
            int node = base + nl;
            float v = (k < K && node < N) ? X[(size_t)node * K + k] : 0.f;
            xs[nl * KS + ((k + nl) & (KS - 1))] = v;
        }
    }
    __syncthreads();
    int wid = __builtin_amdgcn_readfirstlane(t >> 6);   // force scalar
    int lane = t & 63;
    int node = base + lane;
    float acc[16];
#pragma unroll
    for (int j = 0; j < 16; ++j) acc[j] = 0.f;
    const float* Wg = W + wid * 16;
    const float* xrow = xs + lane * KS;
#pragma unroll 4
    for (int k = 0; k < K; ++k) {
        float xk = xrow[(k + lane) & (KS - 1)];
#pragma unroll
        for (int j = 0; j < 16; ++j)
            acc[j] = fmaf(xk, Wg[k * 64 + j], acc[j]);
    }
    float s = 0.f, d = 0.f;
#pragma unroll
    for (int j = 0; j < 16; ++j) {
        s = fmaf(acc[j], asrc[wid * 16 + j], s);
        d = fmaf(acc[j], adst[wid * 16 + j], d);
    }
    ps[0][wid][lane] = s;
    ps[1][wid][lane] = d;
#pragma unroll
    for (int j = 0; j < 16; j += 4) {
        int q = (wid * 16 + j) >> 2;            // quad index 0..15
        int sp = (q + lane) & 15;
        int u = __builtin_amdgcn_cvt_pk_fp8_f32(acc[j], acc[j + 1], 0, false);
        u = __builtin_amdgcn_cvt_pk_fp8_f32(acc[j + 2], acc[j + 3], u, true);
        hsq[lane * 17 + sp] = (unsigned)u;
    }
    __syncthreads();
    if (wid == 0) {
        float s4 = ps[0][0][lane] + ps[0][1][lane] + ps[0][2][lane] + ps[0][3][lane];
        float d4 = ps[1][0][lane] + ps[1][1][lane] + ps[1][2][lane] + ps[1][3][lane];
        if (node < N) { as_[node] = s4; ad_[node] = d4; }
    }
    unsigned* hout = (unsigned*)h;
    for (int pass = 0; pass < 4; ++pass) {
        int row = pass * 16 + (t >> 4);
        int q = t & 15;
        int sp = (q + row) & 15;
        unsigned v = hsq[row * 17 + sp];
        int n2 = base + row;
        if (n2 < N) hout[(size_t)n2 * 16 + q] = v;
    }
}

// ---------------- csr unit (one 256-node bucket) ---------------------------
__device__ __forceinline__ void csr_unit(
    unsigned char* SMEM, int b,
    const int* __restrict__ bcur, const unsigned* __restrict__ part,
    int* __restrict__ csr, int2* __restrict__ offlen, int N) {
    int* hist = (int*)SMEM;            // 256 ints
    int* sc = (int*)(SMEM + 1024);     // 256 ints
    int t = threadIdx.x;
    int nodeBase = b << BSHIFT;
    int nNodes = min(BNODES, N - nodeBase);
    int count = min(bcur[b] - b * ECAP, ECAP);
    hist[t] = (t < nNodes) ? 1 : 0;      // self-loop
    __syncthreads();
    const unsigned* slice = part + (size_t)b * ECAP;
    for (int i = t; i < count; i += 256) {
        int dl = (int)(slice[i] >> 17);
        atomicAdd(&hist[dl], 1);
    }
    __syncthreads();
    int cnt = hist[t];
    sc[t] = cnt;
    __syncthreads();
    for (int o = 1; o < 256; o <<= 1) {
        int v = sc[t];
        int u = (t >= o) ? sc[t - o] : 0;
        __syncthreads();
        sc[t] = v + u;
        __syncthreads();
    }
    int excl = sc[t] - cnt;              // exclusive scan
    int boff = b * CCAP;
    if (t < nNodes) {
        offlen[nodeBase + t] = make_int2(boff + excl, cnt);
        csr[boff + excl] = nodeBase + t; // self loop first
    }
    hist[t] = excl + 1;                  // running local cursor
    __syncthreads();
    for (int i = t; i < count; i += 256) {
        unsigned e = slice[i];
        int dl = (int)(e >> 17);
        int pos = boff + atomicAdd(&hist[dl], 1);
        csr[pos] = (int)(e & 0x1ffffu);
    }
}

// ---------------- agg unit (8 nodes; verbatim R6 structure) ---------------
template<int MODE>
__device__ __forceinline__ void agg_unit(
    unsigned char* SMEM, int unit,
    const int2* __restrict__ offlen, const int* __restrict__ csr,
    const float* __restrict__ as_, const float* __restrict__ ad_,
    const unsigned char* __restrict__ hsrc, const float* __restrict__ bias,
    ushort* __restrict__ out_, float* __restrict__ bacc, int n) {
    int wid = threadIdx.x >> 6, lane = threadIdx.x & 63;
    int half = lane >> 5;            // which node of the wave's pair
    int lh = lane & 31;              // lane within node
    int g = lh >> 3;                 // edge group within half (0..3)
    int l = lane & 7;                // dim-chunk index
    int hw = wid * 2 + half;
    int node = unit * 8 + hw;
    int base_lane = lane & 32;       // first lane of this half
    float v[8];
#pragma unroll
    for (int j = 0; j < 8; ++j) v[j] = 0.f;
    if (node < n) {
        int2 ol = offlen[node];
        int off = ol.x, len = ol.y;
        float adi = ad_[node];
        // ---- lane-parallel meta prefetch (edge lh, covers e<32) ----
        bool vpre = lh < len;
        int skpre = vpre ? csr[off + lh] : 0;
        float apre = vpre ? as_[skpre] : 0.f;
        float tpre = apre + adi;
        tpre = (tpre > 0.f) ? tpre : LRELU_SLOPE * tpre;
        float expre = vpre ? __expf(tpre) : 0.f;
        float den = expre;
        den += __shfl_xor(den, 1);
        den += __shfl_xor(den, 2);
        den += __shfl_xor(den, 4);
        den += __shfl_xor(den, 8);
        den += __shfl_xor(den, 16);
        float acc[8];
#pragma unroll
        for (int j = 0; j < 8; ++j) acc[j] = 0.f;
        if (__all(len <= 32)) {
            // fast path (wave-uniform): all gathers issued upfront
            uint2 hv[8];
            float exs[8];
#pragma unroll
            for (int c = 0; c < 8; ++c) {
                int e = c * 4 + g;              // e <= 31
                int sk = __shfl(skpre, base_lane + e);      // full-wave exec
                exs[c] = __shfl(expre, base_lane + e);      // 0 for e>=len
                const uint2* p = (const uint2*)(hsrc + ((size_t)sk << 6) + (l << 3));
                hv[c] = (e < len) ? *p : make_uint2(0u, 0u);
            }
#pragma unroll
            for (int c = 0; c < 8; ++c) {
                float ex = exs[c];              // 0 => contributes nothing
                f32x2 p0 = __builtin_amdgcn_cvt_pk_f32_fp8(hv[c].x, false);
                f32x2 p1 = __builtin_amdgcn_cvt_pk_f32_fp8(hv[c].x, true);
                f32x2 p2 = __builtin_amdgcn_cvt_pk_f32_fp8(hv[c].y, false);
                f32x2 p3 = __builtin_amdgcn_cvt_pk_f32_fp8(hv[c].y, true);
                acc[0] = fmaf(ex, p0.x, acc[0]);
                acc[1] = fmaf(ex, p0.y, acc[1]);
                acc[2] = fmaf(ex, p1.x, acc[2]);
                acc[3] = fmaf(ex, p1.y, acc[3]);
                acc[4] = fmaf(ex, p2.x, acc[4]);
                acc[5] = fmaf(ex, p2.y, acc[5]);
                acc[6] = fmaf(ex, p3.x, acc[6]);
                acc[7] = fmaf(ex, p3.y, acc[7]);
            }
        } else {
            // slow path (rare): 2-deep pipelined loop
            float den_tail = 0.f;
            int niter = (len + 3) >> 2;
            int sk0 = __shfl(skpre, base_lane + g);
            float ex0 = __shfl(expre, base_lane + g);
            bool ve0 = g < len;
            uint2 hv0 = make_uint2(0, 0);
            if (ve0) hv0 = *(const uint2*)(hsrc + ((size_t)sk0 << 6) + (l << 3));
            int sk1 = __shfl(skpre, base_lane + 4 + g);
            float ex1 = __shfl(expre, base_lane + 4 + g);
            bool ve1 = (4 + g) < len;
            uint2 hv1 = make_uint2(0, 0);
            if (ve1) hv1 = *(const uint2*)(hsrc + ((size_t)sk1 << 6) + (l << 3));
            for (int i = 0; i < niter; ++i) {
                float ex = ex0;
                uint2 hv = hv0;
                ex0 = ex1; hv0 = hv1;
                int e2 = (i + 2) * 4 + g;
                bool ve2 = e2 < len;
                int esrc = e2 < 32 ? e2 : 31;
                sk1 = __shfl(skpre, base_lane + esrc);
                ex1 = __shfl(expre, base_lane + esrc);
                if (e2 >= 32) {
                    if (ve2) {
                        sk1 = csr[off + e2];
                        float a = as_[sk1];
                        float tt = a + adi;
                        tt = (tt > 0.f) ? tt : LRELU_SLOPE * tt;
                        ex1 = __expf(tt);
                        den_tail += ex1;
                    } else ex1 = 0.f;
                }
                hv1 = make_uint2(0, 0);
                if (ve2) hv1 = *(const uint2*)(hsrc + ((size_t)sk1 << 6) + (l << 3));
                f32x2 p0 = __builtin_amdgcn_cvt_pk_f32_fp8(hv.x, false);
                f32x2 p1 = __builtin_amdgcn_cvt_pk_f32_fp8(hv.x, true);
                f32x2 p2 = __builtin_amdgcn_cvt_pk_f32_fp8(hv.y, false);
                f32x2 p3 = __builtin_amdgcn_cvt_pk_f32_fp8(hv.y, true);
                acc[0] = fmaf(ex, p0.x, acc[0]);
                acc[1] = fmaf(ex, p0.y, acc[1]);
                acc[2] = fmaf(ex, p1.x, acc[2]);
                acc[3] = fmaf(ex, p1.y, acc[3]);
                acc[4] = fmaf(ex, p2.x, acc[4]);
                acc[5] = fmaf(ex, p2.y, acc[5]);
                acc[6] = fmaf(ex, p3.x, acc[6]);
                acc[7] = fmaf(ex, p3.y, acc[7]);
            }
            den_tail += __shfl_xor(den_tail, 8);
            den_tail += __shfl_xor(den_tail, 16);
            den += den_tail;
        }
#pragma unroll
        for (int j = 0; j < 8; ++j) {
            acc[j] += __shfl_xor(acc[j], 8);
            acc[j] += __shfl_xor(acc[j], 16);
        }
        float inv = 1.f / den;
        const float4 bv0 = *(const float4*)(bias + l * 8);
        const float4 bv1 = *(const float4*)(bias + l * 8 + 4);
        v[0] = fmaf(acc[0], inv, bv0.x);
        v[1] = fmaf(acc[1], inv, bv0.y);
        v[2] = fmaf(acc[2], inv, bv0.z);
        v[3] = fmaf(acc[3], inv, bv0.w);
        v[4] = fmaf(acc[4], inv, bv1.x);
        v[5] = fmaf(acc[5], inv, bv1.y);
        v[6] = fmaf(acc[6], inv, bv1.z);
        v[7] = fmaf(acc[7], inv, bv1.w);
        if (MODE == 1) {
#pragma unroll
            for (int j = 0; j < 8; ++j) v[j] = fmaxf(v[j], 0.f);
            if (g == 0) {
                uint4 pk;
                pk.x = (unsigned)f2bf(v[0]) | ((unsigned)f2bf(v[1]) << 16);
                pk.y = (unsigned)f2bf(v[2]) | ((unsigned)f2bf(v[3]) << 16);
                pk.z = (unsigned)f2bf(v[4]) | ((unsigned)f2bf(v[5]) << 16);
                pk.w = (unsigned)f2bf(v[6]) | ((unsigned)f2bf(v[7]) << 16);
                *(uint4*)(out_ + (size_t)node * NDIM + l * 8) = pk;
            }
        }
    }
    if (MODE == 2) {
        auto psum = (float(*)[NDIM])SMEM;       // [8][64]
        if (g == 0) {
#pragma unroll
            for (int j = 0; j < 8; ++j) psum[hw][l * 8 + j] = v[j];
        }
        __syncthreads();
        if (threadIdx.x < NDIM) {
            float s = 0.f;
#pragma unroll
            for (int r = 0; r < 8; ++r) s += psum[r][threadIdx.x];
            bacc[threadIdx.x] += s;
        }
        __syncthreads();
    }
}

// ---------------- the whole pipeline as one cooperative kernel -------------
__global__ __launch_bounds__(256, 4) void giga_kernel(
    const int* __restrict__ src, const int* __restrict__ dst,
    int* __restrict__ bcur, unsigned* __restrict__ part,
    int E, int nb, int PB, int GB, int AU,
    const float* __restrict__ x,
    const float* __restrict__ W1, const float* __restrict__ as1v,
    const float* __restrict__ ad1v, const float* __restrict__ b1,
    const float* __restrict__ W2, const float* __restrict__ as2v,
    const float* __restrict__ ad2v, const float* __restrict__ b2,
    unsigned char* __restrict__ h, ushort* __restrict__ o,
    float* __restrict__ as_, float* __restrict__ ad_,
    int2* __restrict__ offlen, int* __restrict__ csr,
    float* __restrict__ out, int N, float invn) {
    __shared__ __align__(16) unsigned char SMEM[SMEM_BYTES];
    cg::grid_group grid = cg::this_grid();
    int t = threadIdx.x;
    int G = gridDim.x;

    // phase 0: init bucket cursors
    for (int i = blockIdx.x * 256 + t; i < nb; i += G * 256) bcur[i] = i * ECAP;
    grid.sync();

    // phase 1: partition + layer-1 GEMM (independent, co-scheduled)
    for (int u = blockIdx.x; u < PB + GB; u += G) {
        if (u < PB) part_unit(SMEM, u, src, dst, bcur, part, E, nb);
        else gemm_unit<20, 32, false>(SMEM, (u - PB) * 64, x, W1, as1v, ad1v, h, as_, ad_, N);
        __syncthreads();          // SMEM reuse across units
    }
    grid.sync();

    // phase 2: per-bucket CSR build
    for (int u = blockIdx.x; u < nb; u += G) {
        csr_unit(SMEM, u, bcur, part, csr, offlen, N);
        __syncthreads();
    }
    grid.sync();

    // phase 3: layer-1 aggregation (writes o bf16)
    for (int u = blockIdx.x; u < AU; u += G)
        agg_unit<1>(SMEM, u, offlen, csr, as_, ad_, h, b1, o, nullptr, N);
    grid.sync();

    // phase 4: layer-2 GEMM (reads o, overwrites h/as/ad)
    for (int u = blockIdx.x; u < GB; u += G) {
        gemm_unit<64, 64, true>(SMEM, u * 64, o, W2, as2v, ad2v, h, as_, ad_, N);
        __syncthreads();
    }
    grid.sync();

    // phase 5: layer-2 aggregation + block-local pool + atomic mean
    float* bacc = (float*)(SMEM + 2048);
    if (t < NDIM) bacc[t] = 0.f;
    __syncthreads();
    for (int u = blockIdx.x; u < AU; u += G)
        agg_unit<2>(SMEM, u, offlen, csr, as_, ad_, h, b2, o, bacc, N);
    if (t < NDIM) {
        float s = bacc[t];
        if (s != 0.f) atomicAdd(&out[t], s * invn);
        else atomicAdd(&out[t], s * invn);   // keep deterministic add count
    }
}

extern "C" void kernel_launch(void* const* d_in, const int* in_sizes, int n_in,
                              void* d_out, int out_size, void* d_ws, size_t ws_size,
                              hipStream_t stream) {
    const float* x      = (const float*)d_in[0];
    const int*   eidx   = (const int*)d_in[1];
    const float* W1     = (const float*)d_in[2];
    const float* a_src1 = (const float*)d_in[3];
    const float* a_dst1 = (const float*)d_in[4];
    const float* b1     = (const float*)d_in[5];
    const float* W2     = (const float*)d_in[6];
    const float* a_src2 = (const float*)d_in[7];
    const float* a_dst2 = (const float*)d_in[8];
    const float* b2     = (const float*)d_in[9];
    float* out = (float*)d_out;

    const int N = in_sizes[0] / 20;      // 100000 (< 2^17, required by u32 part pack)
    const int E = in_sizes[1] / 2;       // 1000000
    const int* src = eidx;
    const int* dst = eidx + E;
    const int NB = (N + BNODES - 1) >> BSHIFT;   // 391
    const int GB = (N + 63) / 64;                // 1563 gemm tiles
    const int AU = (N + 7) / 8;                  // 12500 agg units
    const int PB = (E + 4095) / 4096;            // 245 partition units

    // workspace layout
    char* ws = (char*)d_ws;
    unsigned char* h = (unsigned char*)ws;            // N*64 fp8 (6.4 MB)
    ushort* o   = (ushort*)(h + (size_t)N * NDIM);    // N*64 bf16 (12.8 MB)
    float* as_  = (float*)(o + (size_t)N * NDIM);     // N
    float* ad_  = as_ + N;                            // N
    int2*  offlen = (int2*)(ad_ + N);                 // N
    int*   csr  = (int*)(offlen + N);                 // NB*CCAP
    int*   bcur = (int*)(csr + (size_t)NB * CCAP);    // NB
    unsigned* part = (unsigned*)(bcur + NB);          // NB*ECAP u32 (5.6 MB)

    hipMemsetAsync(d_out, 0, (size_t)out_size * sizeof(float), stream);

    // cooperative grid sizing: never exceed co-residency capacity (fails
    // loudly via launch error rather than hanging)
    int bpc = 0;
    hipOccupancyMaxActiveBlocksPerMultiprocessor(&bpc, giga_kernel, 256, 0);
    if (bpc < 1) bpc = 1;
    int G = bpc * 256;                   // 256 CUs on MI355X
    if (G > 2048) G = 2048;

    float invn = 1.0f / (float)N;
    void* args[] = {
        (void*)&src, (void*)&dst, (void*)&bcur, (void*)&part,
        (void*)&E, (void*)&NB, (void*)&PB, (void*)&GB, (void*)&AU,
        (void*)&x,
        (void*)&W1, (void*)&a_src1, (void*)&a_dst1, (void*)&b1,
        (void*)&W2, (void*)&a_src2, (void*)&a_dst2, (void*)&b2,
        (void*)&h, (void*)&o, (void*)&as_, (void*)&ad_,
        (void*)&offlen, (void*)&csr,
        (void*)&out, (void*)&N, (void*)&invn,
    };
    hipLaunchCooperativeKernel((const void*)giga_kernel, dim3(G), dim3(256),
                               args, 0, stream);
}

// Round 8
// 193.821 us; speedup vs baseline: 2.8537x; 2.8537x over previous
//
#include <hip/hip_runtime.h>
#include <math.h>

#define NDIM 64
#define LRELU_SLOPE 0.2f
#define BSHIFT 8               // 256 nodes per bucket
#define BNODES 256
#define ECAP 3584              // edge capacity per bucket (mean 2558, ~20 sigma headroom)
#define CCAP (ECAP + BNODES)   // csr capacity per bucket (edges + self loops)

typedef float f32x2 __attribute__((ext_vector_type(2)));

__device__ __forceinline__ ushort f2bf(float f) {
    unsigned u = __float_as_uint(f);
    unsigned r = (u + 0x7fffu + ((u >> 16) & 1u)) >> 16;   // RTNE
    return (ushort)r;
}
__device__ __forceinline__ float bflo(unsigned u) { return __uint_as_float(u << 16); }
__device__ __forceinline__ float bfhi(unsigned u) { return __uint_as_float(u & 0xffff0000u); }

// ---------------- fused partition + layer-1 GEMM (one dispatch) -----------
// blocks [0,PB): partition edges into dst-buckets (packed u32 dl<<17|s).
//   2048 edges/block (489 blocks: better CU fill than 245).
//   bcur is ZERO-initialized by hipMemsetAsync (0-based cursors).
// blocks [PB,PB+gemm_blocks): j-split GEMM layer 1 (K=20 fp32 input).
__global__ __launch_bounds__(256) void pg_kernel(
    const int* __restrict__ src, const int* __restrict__ dst,
    int* __restrict__ bcur, unsigned* __restrict__ part, int E, int nb, int PB,
    const float* __restrict__ X, const float* __restrict__ W,
    const float* __restrict__ asrc, const float* __restrict__ adst,
    unsigned char* __restrict__ h, float* __restrict__ as_,
    float* __restrict__ ad_, int N) {
    int t = threadIdx.x;
    if ((int)blockIdx.x < PB) {
        // ---- partition branch (2048 edges) ----
        __shared__ int hist[512];
        __shared__ int base[512];
        for (int i = t; i < nb; i += 256) hist[i] = 0;
        __syncthreads();
        int chunk = blockIdx.x * 2048;
        int s[8], d[8];
#pragma unroll
        for (int j = 0; j < 2; ++j) {
            int idx = chunk + j * 1024 + t * 4;
            if (idx + 3 < E) {
                int4 sv = *(const int4*)(src + idx);
                int4 dv = *(const int4*)(dst + idx);
                s[j*4+0]=sv.x; s[j*4+1]=sv.y; s[j*4+2]=sv.z; s[j*4+3]=sv.w;
                d[j*4+0]=dv.x; d[j*4+1]=dv.y; d[j*4+2]=dv.z; d[j*4+3]=dv.w;
            } else {
#pragma unroll
                for (int q = 0; q < 4; ++q) {
                    int i2 = idx + q;
                    if (i2 < E) { s[j*4+q] = src[i2]; d[j*4+q] = dst[i2]; }
                    else        { s[j*4+q] = 0;       d[j*4+q] = -1; }
                }
            }
        }
#pragma unroll
        for (int j = 0; j < 8; ++j)
            if (d[j] >= 0) atomicAdd(&hist[d[j] >> BSHIFT], 1);
        __syncthreads();
        for (int i = t; i < nb; i += 256) {
            int c = hist[i];
            base[i] = c ? atomicAdd(&bcur[i], c) : 0;   // 0-based local offset
            hist[i] = 0;          // reuse as running cursor
        }
        __syncthreads();
#pragma unroll
        for (int j = 0; j < 8; ++j) {
            if (d[j] >= 0) {
                int b = d[j] >> BSHIFT;
                int loc = base[b] + atomicAdd(&hist[b], 1);
                if (loc > ECAP - 1) loc = ECAP - 1;   // never fires statistically
                part[(size_t)b * ECAP + loc] =
                    ((unsigned)(d[j] & (BNODES - 1)) << 17) | (unsigned)s[j];
            }
        }
    } else {
        // ---- layer-1 GEMM branch (K=20, KS=32, fp32 input) ----
        const int K = 20, KS = 32;
        __shared__ float xs[64 * 32];
        __shared__ unsigned hsq[64 * 17];
        __shared__ float ps[2][4][64];
        int base2 = (blockIdx.x - PB) * 64;
        for (int i = t; i < 64 * KS; i += 256) {
            int nl = i / KS, k = i - nl * KS;
            int node = base2 + nl;
            float v = (k < K && node < N) ? X[(size_t)node * K + k] : 0.f;
            xs[nl * KS + ((k + nl) & (KS - 1))] = v;
        }
        __syncthreads();
        int wid = __builtin_amdgcn_readfirstlane(t >> 6);
        int lane = t & 63;
        int node = base2 + lane;
        float acc[16];
#pragma unroll
        for (int j = 0; j < 16; ++j) acc[j] = 0.f;
        const float* Wg = W + wid * 16;
        const float* xrow = xs + lane * KS;
#pragma unroll 4
        for (int k = 0; k < K; ++k) {
            float xk = xrow[(k + lane) & (KS - 1)];
#pragma unroll
            for (int j = 0; j < 16; ++j)
                acc[j] = fmaf(xk, Wg[k * 64 + j], acc[j]);
        }
        float s = 0.f, d = 0.f;
#pragma unroll
        for (int j = 0; j < 16; ++j) {
            s = fmaf(acc[j], asrc[wid * 16 + j], s);
            d = fmaf(acc[j], adst[wid * 16 + j], d);
        }
        ps[0][wid][lane] = s;
        ps[1][wid][lane] = d;
#pragma unroll
        for (int j = 0; j < 16; j += 4) {
            int q = (wid * 16 + j) >> 2;
            int sp = (q + lane) & 15;
            int u = __builtin_amdgcn_cvt_pk_fp8_f32(acc[j], acc[j + 1], 0, false);
            u = __builtin_amdgcn_cvt_pk_fp8_f32(acc[j + 2], acc[j + 3], u, true);
            hsq[lane * 17 + sp] = (unsigned)u;
        }
        __syncthreads();
        if (wid == 0) {
            float s4 = ps[0][0][lane] + ps[0][1][lane] + ps[0][2][lane] + ps[0][3][lane];
            float d4 = ps[1][0][lane] + ps[1][1][lane] + ps[1][2][lane] + ps[1][3][lane];
            if (node < N) { as_[node] = s4; ad_[node] = d4; }
        }
        unsigned* hout = (unsigned*)h;
        for (int pass = 0; pass < 4; ++pass) {
            int row = pass * 16 + (t >> 4);
            int q = t & 15;
            int sp = (q + row) & 15;
            unsigned v = hsq[row * 17 + sp];
            int n2 = base2 + row;
            if (n2 < N) hout[(size_t)n2 * 16 + q] = v;
        }
    }
}

// ---------------- per-bucket CSR build (+ atil precompute in block 0) ------
__global__ __launch_bounds__(256) void csr_kernel(
    const int* __restrict__ bcur, const unsigned* __restrict__ part,
    int* __restrict__ csr, int2* __restrict__ offlen, int N,
    const float* __restrict__ W2, const float* __restrict__ a_src2,
    const float* __restrict__ a_dst2, float* __restrict__ atil) {
    __shared__ int hist[256];
    __shared__ int sc[256];
    int b = blockIdx.x, t = threadIdx.x;
    int nodeBase = b << BSHIFT;
    int nNodes = min(BNODES, N - nodeBase);
    int count = min(bcur[b], ECAP);
    hist[t] = (t < nNodes) ? 1 : 0;      // self-loop
    __syncthreads();
    const unsigned* slice = part + (size_t)b * ECAP;
    for (int i = t; i < count; i += 256) {
        int dl = (int)(slice[i] >> 17);
        atomicAdd(&hist[dl], 1);
    }
    __syncthreads();
    int cnt = hist[t];
    sc[t] = cnt;
    __syncthreads();
    for (int o = 1; o < 256; o <<= 1) {
        int v = sc[t];
        int u = (t >= o) ? sc[t - o] : 0;
        __syncthreads();
        sc[t] = v + u;
        __syncthreads();
    }
    int excl = sc[t] - cnt;              // exclusive scan
    int boff = b * CCAP;
    if (t < nNodes) {
        offlen[nodeBase + t] = make_int2(boff + excl, cnt);
        csr[boff + excl] = nodeBase + t; // self loop first
    }
    hist[t] = excl + 1;                  // running local cursor
    __syncthreads();
    for (int i = t; i < count; i += 256) {
        unsigned e = slice[i];
        int dl = (int)(e >> 17);
        int pos = boff + atomicAdd(&hist[dl], 1);
        csr[pos] = (int)(e & 0x1ffffu);
    }
    // ---- block 0 extra: atil[j] = W2[j,:]·a_src2 (0..63), ·a_dst2 (64..127)
    // (layer-2 logit projections folded to o-space: as2 = o · atil_s)
    if (b == 0 && t < 128) {
        int j = t & 63;
        const float* av = (t < 64) ? a_src2 : a_dst2;
        const float* wr = W2 + (size_t)j * 64;
        float s = 0.f;
#pragma unroll 8
        for (int k = 0; k < 64; ++k) s = fmaf(wr[k], av[k], s);
        atil[t] = s;
    }
}

// ---------------- layer-1 aggregation (+ layer-2 logit epilogue) -----------
// TWO nodes per wave (32 lanes each). Meta prefetch + wave-uniform 8-deep
// gather MLP (verified R6 structure). Epilogue additionally computes
// as2 = o·atil_s, ad2 = o·atil_d from the in-register o row.
__global__ __launch_bounds__(256) void agg1_kernel(
    const int2* __restrict__ offlen, const int* __restrict__ csr,
    const float* __restrict__ as_, const float* __restrict__ ad_,
    const unsigned char* __restrict__ hsrc, const float* __restrict__ bias,
    const float* __restrict__ atil,
    ushort* __restrict__ out, float* __restrict__ as2,
    float* __restrict__ ad2, int n) {
    int wid = threadIdx.x >> 6, lane = threadIdx.x & 63;
    int half = lane >> 5;            // which node of the wave's pair
    int lh = lane & 31;              // lane within node
    int g = lh >> 3;                 // edge group within half (0..3)
    int l = lane & 7;                // dim-chunk index
    int hw = wid * 2 + half;
    int node = blockIdx.x * 8 + hw;
    int base_lane = lane & 32;       // first lane of this half
    if (node < n) {
        int2 ol = offlen[node];
        int off = ol.x, len = ol.y;
        float adi = ad_[node];
        bool vpre = lh < len;
        int skpre = vpre ? csr[off + lh] : 0;
        float apre = vpre ? as_[skpre] : 0.f;
        float tpre = apre + adi;
        tpre = (tpre > 0.f) ? tpre : LRELU_SLOPE * tpre;
        float expre = vpre ? __expf(tpre) : 0.f;
        float den = expre;
        den += __shfl_xor(den, 1);
        den += __shfl_xor(den, 2);
        den += __shfl_xor(den, 4);
        den += __shfl_xor(den, 8);
        den += __shfl_xor(den, 16);
        float acc[8];
#pragma unroll
        for (int j = 0; j < 8; ++j) acc[j] = 0.f;
        if (__all(len <= 32)) {
            uint2 hv[8];
            float exs[8];
#pragma unroll
            for (int c = 0; c < 8; ++c) {
                int e = c * 4 + g;              // e <= 31
                int sk = __shfl(skpre, base_lane + e);      // full-wave exec
                exs[c] = __shfl(expre, base_lane + e);      // 0 for e>=len
                const uint2* p = (const uint2*)(hsrc + ((size_t)sk << 6) + (l << 3));
                hv[c] = (e < len) ? *p : make_uint2(0u, 0u);
            }
#pragma unroll
            for (int c = 0; c < 8; ++c) {
                float ex = exs[c];
                f32x2 p0 = __builtin_amdgcn_cvt_pk_f32_fp8(hv[c].x, false);
                f32x2 p1 = __builtin_amdgcn_cvt_pk_f32_fp8(hv[c].x, true);
                f32x2 p2 = __builtin_amdgcn_cvt_pk_f32_fp8(hv[c].y, false);
                f32x2 p3 = __builtin_amdgcn_cvt_pk_f32_fp8(hv[c].y, true);
                acc[0] = fmaf(ex, p0.x, acc[0]);
                acc[1] = fmaf(ex, p0.y, acc[1]);
                acc[2] = fmaf(ex, p1.x, acc[2]);
                acc[3] = fmaf(ex, p1.y, acc[3]);
                acc[4] = fmaf(ex, p2.x, acc[4]);
                acc[5] = fmaf(ex, p2.y, acc[5]);
                acc[6] = fmaf(ex, p3.x, acc[6]);
                acc[7] = fmaf(ex, p3.y, acc[7]);
            }
        } else {
            float den_tail = 0.f;
            int niter = (len + 3) >> 2;
            int sk0 = __shfl(skpre, base_lane + g);
            float ex0 = __shfl(expre, base_lane + g);
            bool ve0 = g < len;
            uint2 hv0 = make_uint2(0, 0);
            if (ve0) hv0 = *(const uint2*)(hsrc + ((size_t)sk0 << 6) + (l << 3));
            int sk1 = __shfl(skpre, base_lane + 4 + g);
            float ex1 = __shfl(expre, base_lane + 4 + g);
            bool ve1 = (4 + g) < len;
            uint2 hv1 = make_uint2(0, 0);
            if (ve1) hv1 = *(const uint2*)(hsrc + ((size_t)sk1 << 6) + (l << 3));
            for (int i = 0; i < niter; ++i) {
                float ex = ex0;
                uint2 hv = hv0;
                ex0 = ex1; hv0 = hv1;
                int e2 = (i + 2) * 4 + g;
                bool ve2 = e2 < len;
                int esrc = e2 < 32 ? e2 : 31;
                sk1 = __shfl(skpre, base_lane + esrc);
                ex1 = __shfl(expre, base_lane + esrc);
                if (e2 >= 32) {
                    if (ve2) {
                        sk1 = csr[off + e2];
                        float a = as_[sk1];
                        float tt = a + adi;
                        tt = (tt > 0.f) ? tt : LRELU_SLOPE * tt;
                        ex1 = __expf(tt);
                        den_tail += ex1;
                    } else ex1 = 0.f;
                }
                hv1 = make_uint2(0, 0);
                if (ve2) hv1 = *(const uint2*)(hsrc + ((size_t)sk1 << 6) + (l << 3));
                f32x2 p0 = __builtin_amdgcn_cvt_pk_f32_fp8(hv.x, false);
                f32x2 p1 = __builtin_amdgcn_cvt_pk_f32_fp8(hv.x, true);
                f32x2 p2 = __builtin_amdgcn_cvt_pk_f32_fp8(hv.y, false);
                f32x2 p3 = __builtin_amdgcn_cvt_pk_f32_fp8(hv.y, true);
                acc[0] = fmaf(ex, p0.x, acc[0]);
                acc[1] = fmaf(ex, p0.y, acc[1]);
                acc[2] = fmaf(ex, p1.x, acc[2]);
                acc[3] = fmaf(ex, p1.y, acc[3]);
                acc[4] = fmaf(ex, p2.x, acc[4]);
                acc[5] = fmaf(ex, p2.y, acc[5]);
                acc[6] = fmaf(ex, p3.x, acc[6]);
                acc[7] = fmaf(ex, p3.y, acc[7]);
            }
            den_tail += __shfl_xor(den_tail, 8);
            den_tail += __shfl_xor(den_tail, 16);
            den += den_tail;
        }
#pragma unroll
        for (int j = 0; j < 8; ++j) {
            acc[j] += __shfl_xor(acc[j], 8);
            acc[j] += __shfl_xor(acc[j], 16);
        }
        float inv = 1.f / den;
        const float4 bv0 = *(const float4*)(bias + l * 8);
        const float4 bv1 = *(const float4*)(bias + l * 8 + 4);
        float v[8];
        v[0] = fmaxf(fmaf(acc[0], inv, bv0.x), 0.f);
        v[1] = fmaxf(fmaf(acc[1], inv, bv0.y), 0.f);
        v[2] = fmaxf(fmaf(acc[2], inv, bv0.z), 0.f);
        v[3] = fmaxf(fmaf(acc[3], inv, bv0.w), 0.f);
        v[4] = fmaxf(fmaf(acc[4], inv, bv1.x), 0.f);
        v[5] = fmaxf(fmaf(acc[5], inv, bv1.y), 0.f);
        v[6] = fmaxf(fmaf(acc[6], inv, bv1.z), 0.f);
        v[7] = fmaxf(fmaf(acc[7], inv, bv1.w), 0.f);
        if (g == 0) {
            uint4 pk;
            pk.x = (unsigned)f2bf(v[0]) | ((unsigned)f2bf(v[1]) << 16);
            pk.y = (unsigned)f2bf(v[2]) | ((unsigned)f2bf(v[3]) << 16);
            pk.z = (unsigned)f2bf(v[4]) | ((unsigned)f2bf(v[5]) << 16);
            pk.w = (unsigned)f2bf(v[6]) | ((unsigned)f2bf(v[7]) << 16);
            *(uint4*)(out + (size_t)node * NDIM + l * 8) = pk;
        }
        // ---- layer-2 logit epilogue: as2 = o·atil_s, ad2 = o·atil_d ----
        const float4 s0 = *(const float4*)(atil + l * 8);
        const float4 s1 = *(const float4*)(atil + l * 8 + 4);
        const float4 d0 = *(const float4*)(atil + 64 + l * 8);
        const float4 d1 = *(const float4*)(atil + 64 + l * 8 + 4);
        float sp = v[0]*s0.x + v[1]*s0.y + v[2]*s0.z + v[3]*s0.w
                 + v[4]*s1.x + v[5]*s1.y + v[6]*s1.z + v[7]*s1.w;
        float dp = v[0]*d0.x + v[1]*d0.y + v[2]*d0.z + v[3]*d0.w
                 + v[4]*d1.x + v[5]*d1.y + v[6]*d1.z + v[7]*d1.w;
        sp += __shfl_xor(sp, 1); sp += __shfl_xor(sp, 2); sp += __shfl_xor(sp, 4);
        dp += __shfl_xor(dp, 1); dp += __shfl_xor(dp, 2); dp += __shfl_xor(dp, 4);
        if (lh == 0) { as2[node] = sp; ad2[node] = dp; }
    }
}

// ---------------- layer-2 aggregation in o-space (z = softmax-avg of o) ----
// Same structure; gathers 128B bf16 o rows via uint4 (8 dims/lane). No bias,
// no W2 (applied once in mean_kernel). Writes per-block pool partials of z.
__global__ __launch_bounds__(256) void agg2_kernel(
    const int2* __restrict__ offlen, const int* __restrict__ csr,
    const float* __restrict__ as_, const float* __restrict__ ad_,
    const ushort* __restrict__ osrc, float* __restrict__ pool, int n) {
    __shared__ float psum[8][NDIM];
    int wid = threadIdx.x >> 6, lane = threadIdx.x & 63;
    int half = lane >> 5;
    int lh = lane & 31;
    int g = lh >> 3;
    int l = lane & 7;
    int hw = wid * 2 + half;
    int node = blockIdx.x * 8 + hw;
    int base_lane = lane & 32;
    float v[8];
#pragma unroll
    for (int j = 0; j < 8; ++j) v[j] = 0.f;
    if (node < n) {
        int2 ol = offlen[node];
        int off = ol.x, len = ol.y;
        float adi = ad_[node];
        bool vpre = lh < len;
        int skpre = vpre ? csr[off + lh] : 0;
        float apre = vpre ? as_[skpre] : 0.f;
        float tpre = apre + adi;
        tpre = (tpre > 0.f) ? tpre : LRELU_SLOPE * tpre;
        float expre = vpre ? __expf(tpre) : 0.f;
        float den = expre;
        den += __shfl_xor(den, 1);
        den += __shfl_xor(den, 2);
        den += __shfl_xor(den, 4);
        den += __shfl_xor(den, 8);
        den += __shfl_xor(den, 16);
        float acc[8];
#pragma unroll
        for (int j = 0; j < 8; ++j) acc[j] = 0.f;
        if (__all(len <= 32)) {
            uint4 hv[8];
            float exs[8];
#pragma unroll
            for (int c = 0; c < 8; ++c) {
                int e = c * 4 + g;
                int sk = __shfl(skpre, base_lane + e);
                exs[c] = __shfl(expre, base_lane + e);
                const uint4* p = (const uint4*)(osrc + ((size_t)sk << 6) + (l << 3));
                hv[c] = (e < len) ? *p : make_uint4(0u, 0u, 0u, 0u);
            }
#pragma unroll
            for (int c = 0; c < 8; ++c) {
                float ex = exs[c];
                acc[0] = fmaf(ex, bflo(hv[c].x), acc[0]);
                acc[1] = fmaf(ex, bfhi(hv[c].x), acc[1]);
                acc[2] = fmaf(ex, bflo(hv[c].y), acc[2]);
                acc[3] = fmaf(ex, bfhi(hv[c].y), acc[3]);
                acc[4] = fmaf(ex, bflo(hv[c].z), acc[4]);
                acc[5] = fmaf(ex, bfhi(hv[c].z), acc[5]);
                acc[6] = fmaf(ex, bflo(hv[c].w), acc[6]);
                acc[7] = fmaf(ex, bfhi(hv[c].w), acc[7]);
            }
        } else {
            float den_tail = 0.f;
            int niter = (len + 3) >> 2;
            int sk0 = __shfl(skpre, base_lane + g);
            float ex0 = __shfl(expre, base_lane + g);
            bool ve0 = g < len;
            uint4 hv0 = make_uint4(0, 0, 0, 0);
            if (ve0) hv0 = *(const uint4*)(osrc + ((size_t)sk0 << 6) + (l << 3));
            int sk1 = __shfl(skpre, base_lane + 4 + g);
            float ex1 = __shfl(expre, base_lane + 4 + g);
            bool ve1 = (4 + g) < len;
            uint4 hv1 = make_uint4(0, 0, 0, 0);
            if (ve1) hv1 = *(const uint4*)(osrc + ((size_t)sk1 << 6) + (l << 3));
            for (int i = 0; i < niter; ++i) {
                float ex = ex0;
                uint4 hv = hv0;
                ex0 = ex1; hv0 = hv1;
                int e2 = (i + 2) * 4 + g;
                bool ve2 = e2 < len;
                int esrc = e2 < 32 ? e2 : 31;
                sk1 = __shfl(skpre, base_lane + esrc);
                ex1 = __shfl(expre, base_lane + esrc);
                if (e2 >= 32) {
                    if (ve2) {
                        sk1 = csr[off + e2];
                        float a = as_[sk1];
                        float tt = a + adi;
                        tt = (tt > 0.f) ? tt : LRELU_SLOPE * tt;
                        ex1 = __expf(tt);
                        den_tail += ex1;
                    } else ex1 = 0.f;
                }
                hv1 = make_uint4(0, 0, 0, 0);
                if (ve2) hv1 = *(const uint4*)(osrc + ((size_t)sk1 << 6) + (l << 3));
                acc[0] = fmaf(ex, bflo(hv.x), acc[0]);
                acc[1] = fmaf(ex, bfhi(hv.x), acc[1]);
                acc[2] = fmaf(ex, bflo(hv.y), acc[2]);
                acc[3] = fmaf(ex, bfhi(hv.y), acc[3]);
                acc[4] = fmaf(ex, bflo(hv.z), acc[4]);
                acc[5] = fmaf(ex, bfhi(hv.z), acc[5]);
                acc[6] = fmaf(ex, bflo(hv.w), acc[6]);
                acc[7] = fmaf(ex, bfhi(hv.w), acc[7]);
            }
            den_tail += __shfl_xor(den_tail, 8);
            den_tail += __shfl_xor(den_tail, 16);
            den += den_tail;
        }
#pragma unroll
        for (int j = 0; j < 8; ++j) {
            acc[j] += __shfl_xor(acc[j], 8);
            acc[j] += __shfl_xor(acc[j], 16);
        }
        float inv = 1.f / den;
#pragma unroll
        for (int j = 0; j < 8; ++j) v[j] = acc[j] * inv;   // z row (no bias)
    }
    if (g == 0) {
#pragma unroll
        for (int j = 0; j < 8; ++j) psum[hw][l * 8 + j] = v[j];
    }
    __syncthreads();
    if (threadIdx.x < NDIM) {
        float t = 0.f;
#pragma unroll
        for (int r = 0; r < 8; ++r) t += psum[r][threadIdx.x];
        pool[(size_t)blockIdx.x * NDIM + threadIdx.x] = t;
    }
}

// ---------------- final mean + layer-2 matvec ------------------------------
// out = W2^T (mean z) + b2, distributed: each block applies W2^T to its
// partial z-sum (linear => commutes), block 0 adds b2 once.
__global__ void mean_kernel(const float* __restrict__ pool,
                            const float* __restrict__ W2,
                            const float* __restrict__ b2,
                            float* __restrict__ out, int nb, float invn) {
    __shared__ float sm[4][NDIM];
    __shared__ float zs[NDIM];
    int lane = threadIdx.x & 63, wid = threadIdx.x >> 6;
    int row = blockIdx.x * 4 + wid;
    int stride = gridDim.x * 4;
    float s = 0.f;
    for (int i = row; i < nb; i += stride) s += pool[(long)i * NDIM + lane];
    sm[wid][lane] = s;
    __syncthreads();
    if (wid == 0) {
        zs[lane] = sm[0][lane] + sm[1][lane] + sm[2][lane] + sm[3][lane];
    }
    __syncthreads();
    if (wid == 0) {
        float y = 0.f;
#pragma unroll 8
        for (int j = 0; j < 64; ++j)
            y = fmaf(zs[j], W2[(size_t)j * 64 + lane], y);   // coalesced over lane
        atomicAdd(&out[lane], y * invn);
        if (blockIdx.x == 0) atomicAdd(&out[lane], b2[lane]);
    }
}

extern "C" void kernel_launch(void* const* d_in, const int* in_sizes, int n_in,
                              void* d_out, int out_size, void* d_ws, size_t ws_size,
                              hipStream_t stream) {
    const float* x      = (const float*)d_in[0];
    const int*   eidx   = (const int*)d_in[1];
    const float* W1     = (const float*)d_in[2];
    const float* a_src1 = (const float*)d_in[3];
    const float* a_dst1 = (const float*)d_in[4];
    const float* b1     = (const float*)d_in[5];
    const float* W2     = (const float*)d_in[6];
    const float* a_src2 = (const float*)d_in[7];
    const float* a_dst2 = (const float*)d_in[8];
    const float* b2     = (const float*)d_in[9];
    float* out = (float*)d_out;

    const int N = in_sizes[0] / 20;      // 100000 (< 2^17, required by u32 part pack)
    const int E = in_sizes[1] / 2;       // 1000000
    const int* src = eidx;
    const int* dst = eidx + E;
    const int NB = (N + BNODES - 1) >> BSHIFT;   // 391

    const int gemm_blocks = (N + 63) / 64;    // 1563 (64 nodes/block)
    const int agg_blocks  = (N + 7) / 8;      // 12500 (8 nodes/block, 2/wave)
    const int PB = (E + 2047) / 2048;         // 489 partition blocks

    // workspace layout
    char* ws = (char*)d_ws;
    unsigned char* h = (unsigned char*)ws;            // N*64 fp8 (6.4 MB), layer-1 only
    ushort* o   = (ushort*)(h + (size_t)N * NDIM);    // N*64 bf16 (12.8 MB)
    float* as1  = (float*)(o + (size_t)N * NDIM);     // N
    float* ad1  = as1 + N;                            // N
    float* as2  = ad1 + N;                            // N
    float* ad2  = as2 + N;                            // N
    int2*  offlen = (int2*)(ad2 + N);                 // N
    int*   csr  = (int*)(offlen + N);                 // NB*CCAP
    float* pool = (float*)(csr + (size_t)NB * CCAP);  // agg_blocks*64
    float* atil = pool + (size_t)agg_blocks * NDIM;   // 128 (16B-aligned)
    int*   bcur = (int*)(atil + 128);                 // NB
    unsigned* part = (unsigned*)(bcur + NB);          // NB*ECAP u32 (5.6 MB)

    // stream-head memsets: out accumulator + 0-based bucket cursors
    hipMemsetAsync(d_out, 0, (size_t)out_size * sizeof(float), stream);
    hipMemsetAsync(bcur, 0, (size_t)NB * sizeof(int), stream);

    // partition + layer-1 GEMM (fused dispatch)
    pg_kernel<<<PB + gemm_blocks, 256, 0, stream>>>(
        src, dst, bcur, part, E, NB, PB,
        x, W1, a_src1, a_dst1, h, as1, ad1, N);
    // per-bucket CSR build (+ atil precompute)
    csr_kernel<<<NB, 256, 0, stream>>>(bcur, part, csr, offlen, N,
                                       W2, a_src2, a_dst2, atil);

    // layer-1 aggregation (writes o, as2, ad2)
    agg1_kernel<<<agg_blocks, 256, 0, stream>>>(
        offlen, csr, as1, ad1, h, b1, atil, o, as2, ad2, N);

    // layer-2 aggregation in o-space (writes pool partials of z)
    agg2_kernel<<<agg_blocks, 256, 0, stream>>>(
        offlen, csr, as2, ad2, o, pool, N);

    // final mean + W2 matvec + b2
    mean_kernel<<<64, 256, 0, stream>>>(pool, W2, b2, out, agg_blocks,
                                        1.0f / (float)N);
}

// Round 9
// 184.512 us; speedup vs baseline: 2.9977x; 1.0505x over previous
//
#include <hip/hip_runtime.h>
#include <math.h>

#define NDIM 64
#define LRELU_SLOPE 0.2f
#define BSHIFT 8               // 256 nodes per bucket
#define BNODES 256
#define ECAP 3584              // edge capacity per bucket (mean 2558, ~20 sigma headroom)
#define CCAP (ECAP + BNODES)   // csr capacity per bucket (edges + self loops)

typedef float f32x2 __attribute__((ext_vector_type(2)));

__device__ __forceinline__ float bflo(unsigned u) { return __uint_as_float(u << 16); }
__device__ __forceinline__ float bfhi(unsigned u) { return __uint_as_float(u & 0xffff0000u); }

// ---------------- fused partition + layer-1 GEMM (one dispatch) -----------
// blocks [0,PB): partition edges into dst-buckets (packed u32 dl<<17|s).
//   2048 edges/block. bcur ZERO-initialized by hipMemsetAsync.
// blocks [PB,PB+gemm_blocks): j-split GEMM layer 1 (K=20 fp32 input).
__global__ __launch_bounds__(256) void pg_kernel(
    const int* __restrict__ src, const int* __restrict__ dst,
    int* __restrict__ bcur, unsigned* __restrict__ part, int E, int nb, int PB,
    const float* __restrict__ X, const float* __restrict__ W,
    const float* __restrict__ asrc, const float* __restrict__ adst,
    unsigned char* __restrict__ h, float* __restrict__ as_,
    float* __restrict__ ad_, int N) {
    int t = threadIdx.x;
    if ((int)blockIdx.x < PB) {
        // ---- partition branch (2048 edges) ----
        __shared__ int hist[512];
        __shared__ int base[512];
        for (int i = t; i < nb; i += 256) hist[i] = 0;
        __syncthreads();
        int chunk = blockIdx.x * 2048;
        int s[8], d[8];
#pragma unroll
        for (int j = 0; j < 2; ++j) {
            int idx = chunk + j * 1024 + t * 4;
            if (idx + 3 < E) {
                int4 sv = *(const int4*)(src + idx);
                int4 dv = *(const int4*)(dst + idx);
                s[j*4+0]=sv.x; s[j*4+1]=sv.y; s[j*4+2]=sv.z; s[j*4+3]=sv.w;
                d[j*4+0]=dv.x; d[j*4+1]=dv.y; d[j*4+2]=dv.z; d[j*4+3]=dv.w;
            } else {
#pragma unroll
                for (int q = 0; q < 4; ++q) {
                    int i2 = idx + q;
                    if (i2 < E) { s[j*4+q] = src[i2]; d[j*4+q] = dst[i2]; }
                    else        { s[j*4+q] = 0;       d[j*4+q] = -1; }
                }
            }
        }
#pragma unroll
        for (int j = 0; j < 8; ++j)
            if (d[j] >= 0) atomicAdd(&hist[d[j] >> BSHIFT], 1);
        __syncthreads();
        for (int i = t; i < nb; i += 256) {
            int c = hist[i];
            base[i] = c ? atomicAdd(&bcur[i], c) : 0;   // 0-based local offset
            hist[i] = 0;          // reuse as running cursor
        }
        __syncthreads();
#pragma unroll
        for (int j = 0; j < 8; ++j) {
            if (d[j] >= 0) {
                int b = d[j] >> BSHIFT;
                int loc = base[b] + atomicAdd(&hist[b], 1);
                if (loc > ECAP - 1) loc = ECAP - 1;   // never fires statistically
                part[(size_t)b * ECAP + loc] =
                    ((unsigned)(d[j] & (BNODES - 1)) << 17) | (unsigned)s[j];
            }
        }
    } else {
        // ---- layer-1 GEMM branch (K=20, KS=32, fp32 input) ----
        const int K = 20, KS = 32;
        __shared__ float xs[64 * 32];
        __shared__ unsigned hsq[64 * 17];
        __shared__ float ps[2][4][64];
        int base2 = (blockIdx.x - PB) * 64;
        for (int i = t; i < 64 * KS; i += 256) {
            int nl = i / KS, k = i - nl * KS;
            int node = base2 + nl;
            float v = (k < K && node < N) ? X[(size_t)node * K + k] : 0.f;
            xs[nl * KS + ((k + nl) & (KS - 1))] = v;
        }
        __syncthreads();
        int wid = __builtin_amdgcn_readfirstlane(t >> 6);
        int lane = t & 63;
        int node = base2 + lane;
        float acc[16];
#pragma unroll
        for (int j = 0; j < 16; ++j) acc[j] = 0.f;
        const float* Wg = W + wid * 16;
        const float* xrow = xs + lane * KS;
#pragma unroll 4
        for (int k = 0; k < K; ++k) {
            float xk = xrow[(k + lane) & (KS - 1)];
#pragma unroll
            for (int j = 0; j < 16; ++j)
                acc[j] = fmaf(xk, Wg[k * 64 + j], acc[j]);
        }
        float s = 0.f, d = 0.f;
#pragma unroll
        for (int j = 0; j < 16; ++j) {
            s = fmaf(acc[j], asrc[wid * 16 + j], s);
            d = fmaf(acc[j], adst[wid * 16 + j], d);
        }
        ps[0][wid][lane] = s;
        ps[1][wid][lane] = d;
#pragma unroll
        for (int j = 0; j < 16; j += 4) {
            int q = (wid * 16 + j) >> 2;
            int sp = (q + lane) & 15;
            int u = __builtin_amdgcn_cvt_pk_fp8_f32(acc[j], acc[j + 1], 0, false);
            u = __builtin_amdgcn_cvt_pk_fp8_f32(acc[j + 2], acc[j + 3], u, true);
            hsq[lane * 17 + sp] = (unsigned)u;
        }
        __syncthreads();
        if (wid == 0) {
            float s4 = ps[0][0][lane] + ps[0][1][lane] + ps[0][2][lane] + ps[0][3][lane];
            float d4 = ps[1][0][lane] + ps[1][1][lane] + ps[1][2][lane] + ps[1][3][lane];
            if (node < N) { as_[node] = s4; ad_[node] = d4; }
        }
        unsigned* hout = (unsigned*)h;
        for (int pass = 0; pass < 4; ++pass) {
            int row = pass * 16 + (t >> 4);
            int q = t & 15;
            int sp = (q + row) & 15;
            unsigned v = hsq[row * 17 + sp];
            int n2 = base2 + row;
            if (n2 < N) hout[(size_t)n2 * 16 + q] = v;
        }
    }
}

// ---------------- per-bucket CSR build (+ atil precompute in block 0) ------
__global__ __launch_bounds__(256) void csr_kernel(
    const int* __restrict__ bcur, const unsigned* __restrict__ part,
    int* __restrict__ csr, int2* __restrict__ offlen, int N,
    const float* __restrict__ W2, const float* __restrict__ a_src2,
    const float* __restrict__ a_dst2, float* __restrict__ atil) {
    __shared__ int hist[256];
    __shared__ int sc[256];
    int b = blockIdx.x, t = threadIdx.x;
    int nodeBase = b << BSHIFT;
    int nNodes = min(BNODES, N - nodeBase);
    int count = min(bcur[b], ECAP);
    hist[t] = (t < nNodes) ? 1 : 0;      // self-loop
    __syncthreads();
    const unsigned* slice = part + (size_t)b * ECAP;
    for (int i = t; i < count; i += 256) {
        int dl = (int)(slice[i] >> 17);
        atomicAdd(&hist[dl], 1);
    }
    __syncthreads();
    int cnt = hist[t];
    sc[t] = cnt;
    __syncthreads();
    for (int o = 1; o < 256; o <<= 1) {
        int v = sc[t];
        int u = (t >= o) ? sc[t - o] : 0;
        __syncthreads();
        sc[t] = v + u;
        __syncthreads();
    }
    int excl = sc[t] - cnt;              // exclusive scan
    int boff = b * CCAP;
    if (t < nNodes) {
        offlen[nodeBase + t] = make_int2(boff + excl, cnt);
        csr[boff + excl] = nodeBase + t; // self loop first
    }
    hist[t] = excl + 1;                  // running local cursor
    __syncthreads();
    for (int i = t; i < count; i += 256) {
        unsigned e = slice[i];
        int dl = (int)(e >> 17);
        int pos = boff + atomicAdd(&hist[dl], 1);
        csr[pos] = (int)(e & 0x1ffffu);
    }
    // ---- block 0 extra: atil[j] = W2[j,:]·a_src2 (0..63), ·a_dst2 (64..127)
    if (b == 0 && t < 128) {
        int j = t & 63;
        const float* av = (t < 64) ? a_src2 : a_dst2;
        const float* wr = W2 + (size_t)j * 64;
        float s = 0.f;
#pragma unroll 8
        for (int k = 0; k < 64; ++k) s = fmaf(wr[k], av[k], s);
        atil[t] = s;
    }
}

// ---------------- shared gather-accumulate core ----------------------------
// Node's 32-lane half: meta-prefetch (lane lh = edge lh), den via butterfly,
// then gather 64B fp8 rows. Issue loop bounded by wave-uniform ceil(lm/4)
// (scalar-branch skip; shuffles full-wave). Consume loop bounded by per-half
// len (register-only; divergence legal). Returns den, fills acc[8].
__device__ __forceinline__ float gather64(
    int off, int len, int lm, float adi, int lh, int g, int l, int base_lane,
    const int* __restrict__ csr, const float* __restrict__ as_,
    const unsigned char* __restrict__ rows, float acc[8]) {
    bool vpre = lh < len;
    int skpre = vpre ? csr[off + lh] : 0;
    float apre = vpre ? as_[skpre] : 0.f;
    float tpre = apre + adi;
    tpre = (tpre > 0.f) ? tpre : LRELU_SLOPE * tpre;
    float expre = vpre ? __expf(tpre) : 0.f;
    float den = expre;
    den += __shfl_xor(den, 1);
    den += __shfl_xor(den, 2);
    den += __shfl_xor(den, 4);
    den += __shfl_xor(den, 8);
    den += __shfl_xor(den, 16);
    f32x2 a01 = {0.f, 0.f}, a23 = {0.f, 0.f}, a45 = {0.f, 0.f}, a67 = {0.f, 0.f};
    if (__all(lm <= 32)) {
        // fast path: compile-time-unrolled; chunk c live iff c*4 < lm
        uint2 hv[8];
        float exs[8];
#pragma unroll
        for (int c = 0; c < 8; ++c) {
            hv[c] = make_uint2(0u, 0u);
            exs[c] = 0.f;
            if (c * 4 < lm) {                    // wave-uniform -> scalar skip
                int e = c * 4 + g;
                int sk = __shfl(skpre, base_lane + e);       // full-wave exec
                exs[c] = __shfl(expre, base_lane + e);       // 0 for e>=len
                if (e < len)
                    hv[c] = *(const uint2*)(rows + ((size_t)sk << 6) + (l << 3));
            }
        }
#pragma unroll
        for (int c = 0; c < 8; ++c) {
            if (c * 4 < len) {                   // per-half uniform, reg-only
                f32x2 ex2 = {exs[c], exs[c]};
                a01 += __builtin_amdgcn_cvt_pk_f32_fp8(hv[c].x, false) * ex2;
                a23 += __builtin_amdgcn_cvt_pk_f32_fp8(hv[c].x, true) * ex2;
                a45 += __builtin_amdgcn_cvt_pk_f32_fp8(hv[c].y, false) * ex2;
                a67 += __builtin_amdgcn_cvt_pk_f32_fp8(hv[c].y, true) * ex2;
            }
        }
    } else {
        // slow path (rare, len>32): 2-deep pipelined loop with den tail
        float den_tail = 0.f;
        int niter = (len + 3) >> 2;
        int sk0 = __shfl(skpre, base_lane + g);
        float ex0 = __shfl(expre, base_lane + g);
        bool ve0 = g < len;
        uint2 hv0 = make_uint2(0, 0);
        if (ve0) hv0 = *(const uint2*)(rows + ((size_t)sk0 << 6) + (l << 3));
        int sk1 = __shfl(skpre, base_lane + 4 + g);
        float ex1 = __shfl(expre, base_lane + 4 + g);
        bool ve1 = (4 + g) < len;
        uint2 hv1 = make_uint2(0, 0);
        if (ve1) hv1 = *(const uint2*)(rows + ((size_t)sk1 << 6) + (l << 3));
        for (int i = 0; i < niter; ++i) {
            float ex = ex0;
            uint2 hv = hv0;
            ex0 = ex1; hv0 = hv1;
            int e2 = (i + 2) * 4 + g;
            bool ve2 = e2 < len;
            int esrc = e2 < 32 ? e2 : 31;
            sk1 = __shfl(skpre, base_lane + esrc);
            ex1 = __shfl(expre, base_lane + esrc);
            if (e2 >= 32) {
                if (ve2) {
                    sk1 = csr[off + e2];
                    float a = as_[sk1];
                    float tt = a + adi;
                    tt = (tt > 0.f) ? tt : LRELU_SLOPE * tt;
                    ex1 = __expf(tt);
                    den_tail += ex1;
                } else ex1 = 0.f;
            }
            hv1 = make_uint2(0, 0);
            if (ve2) hv1 = *(const uint2*)(rows + ((size_t)sk1 << 6) + (l << 3));
            f32x2 ex2 = {ex, ex};
            a01 += __builtin_amdgcn_cvt_pk_f32_fp8(hv.x, false) * ex2;
            a23 += __builtin_amdgcn_cvt_pk_f32_fp8(hv.x, true) * ex2;
            a45 += __builtin_amdgcn_cvt_pk_f32_fp8(hv.y, false) * ex2;
            a67 += __builtin_amdgcn_cvt_pk_f32_fp8(hv.y, true) * ex2;
        }
        den_tail += __shfl_xor(den_tail, 8);
        den_tail += __shfl_xor(den_tail, 16);
        den += den_tail;
    }
    acc[0] = a01.x; acc[1] = a01.y;
    acc[2] = a23.x; acc[3] = a23.y;
    acc[4] = a45.x; acc[5] = a45.y;
    acc[6] = a67.x; acc[7] = a67.y;
    // reduce across the 4 edge-groups of this half (bits 3..4)
#pragma unroll
    for (int j = 0; j < 8; ++j) {
        acc[j] += __shfl_xor(acc[j], 8);
        acc[j] += __shfl_xor(acc[j], 16);
    }
    return den;
}

// ---------------- layer-1 aggregation (+ layer-2 logit epilogue) -----------
// Writes o as fp8 (internal only) + as2/ad2 via the atil projection.
__global__ __launch_bounds__(256) void agg1_kernel(
    const int2* __restrict__ offlen, const int* __restrict__ csr,
    const float* __restrict__ as_, const float* __restrict__ ad_,
    const unsigned char* __restrict__ hsrc, const float* __restrict__ bias,
    const float* __restrict__ atil,
    unsigned char* __restrict__ o8, float* __restrict__ as2,
    float* __restrict__ ad2, int n) {
    int wid = threadIdx.x >> 6, lane = threadIdx.x & 63;
    int half = lane >> 5;
    int lh = lane & 31;
    int g = lh >> 3;
    int l = lane & 7;
    int hw = wid * 2 + half;
    int node = blockIdx.x * 8 + hw;
    int base_lane = lane & 32;
    int nodec = min(node, n - 1);
    int2 ol = offlen[nodec];
    int off = ol.x;
    int len = (node < n) ? ol.y : 0;
    float adi = ad_[nodec];
    int lm = max(len, __shfl_xor(len, 32));      // wave-uniform max
    float acc[8];
    float den = gather64(off, len, lm, adi, lh, g, l, base_lane,
                         csr, as_, hsrc, acc);
    if (node < n) {
        float inv = 1.f / den;
        const float4 bv0 = *(const float4*)(bias + l * 8);
        const float4 bv1 = *(const float4*)(bias + l * 8 + 4);
        float v[8];
        v[0] = fmaxf(fmaf(acc[0], inv, bv0.x), 0.f);
        v[1] = fmaxf(fmaf(acc[1], inv, bv0.y), 0.f);
        v[2] = fmaxf(fmaf(acc[2], inv, bv0.z), 0.f);
        v[3] = fmaxf(fmaf(acc[3], inv, bv0.w), 0.f);
        v[4] = fmaxf(fmaf(acc[4], inv, bv1.x), 0.f);
        v[5] = fmaxf(fmaf(acc[5], inv, bv1.y), 0.f);
        v[6] = fmaxf(fmaf(acc[6], inv, bv1.z), 0.f);
        v[7] = fmaxf(fmaf(acc[7], inv, bv1.w), 0.f);
        if (g == 0) {
            int u0 = __builtin_amdgcn_cvt_pk_fp8_f32(v[0], v[1], 0, false);
            u0 = __builtin_amdgcn_cvt_pk_fp8_f32(v[2], v[3], u0, true);
            int u1 = __builtin_amdgcn_cvt_pk_fp8_f32(v[4], v[5], 0, false);
            u1 = __builtin_amdgcn_cvt_pk_fp8_f32(v[6], v[7], u1, true);
            *(uint2*)(o8 + ((size_t)node << 6) + (l << 3)) =
                make_uint2((unsigned)u0, (unsigned)u1);
        }
        // layer-2 logit epilogue: as2 = o·atil_s, ad2 = o·atil_d (fp32 o)
        const float4 s0 = *(const float4*)(atil + l * 8);
        const float4 s1 = *(const float4*)(atil + l * 8 + 4);
        const float4 d0 = *(const float4*)(atil + 64 + l * 8);
        const float4 d1 = *(const float4*)(atil + 64 + l * 8 + 4);
        float sp = v[0]*s0.x + v[1]*s0.y + v[2]*s0.z + v[3]*s0.w
                 + v[4]*s1.x + v[5]*s1.y + v[6]*s1.z + v[7]*s1.w;
        float dp = v[0]*d0.x + v[1]*d0.y + v[2]*d0.z + v[3]*d0.w
                 + v[4]*d1.x + v[5]*d1.y + v[6]*d1.z + v[7]*d1.w;
        sp += __shfl_xor(sp, 1); sp += __shfl_xor(sp, 2); sp += __shfl_xor(sp, 4);
        dp += __shfl_xor(dp, 1); dp += __shfl_xor(dp, 2); dp += __shfl_xor(dp, 4);
        if (lh == 0) { as2[node] = sp; ad2[node] = dp; }
    }
}

// ---------------- layer-2 aggregation in o-space ---------------------------
// z = softmax-avg of fp8 o rows; per-block pool partials (W2/b2 applied once
// in mean_kernel).
__global__ __launch_bounds__(256) void agg2_kernel(
    const int2* __restrict__ offlen, const int* __restrict__ csr,
    const float* __restrict__ as_, const float* __restrict__ ad_,
    const unsigned char* __restrict__ osrc, float* __restrict__ pool, int n) {
    __shared__ float psum[8][NDIM];
    int wid = threadIdx.x >> 6, lane = threadIdx.x & 63;
    int half = lane >> 5;
    int lh = lane & 31;
    int g = lh >> 3;
    int l = lane & 7;
    int hw = wid * 2 + half;
    int node = blockIdx.x * 8 + hw;
    int base_lane = lane & 32;
    int nodec = min(node, n - 1);
    int2 ol = offlen[nodec];
    int off = ol.x;
    int len = (node < n) ? ol.y : 0;
    float adi = ad_[nodec];
    int lm = max(len, __shfl_xor(len, 32));
    float acc[8];
    float den = gather64(off, len, lm, adi, lh, g, l, base_lane,
                         csr, as_, osrc, acc);
    float v[8];
#pragma unroll
    for (int j = 0; j < 8; ++j) v[j] = 0.f;
    if (node < n) {
        float inv = 1.f / den;
#pragma unroll
        for (int j = 0; j < 8; ++j) v[j] = acc[j] * inv;   // z row
    }
    if (g == 0) {
#pragma unroll
        for (int j = 0; j < 8; ++j) psum[hw][l * 8 + j] = v[j];
    }
    __syncthreads();
    if (threadIdx.x < NDIM) {
        float t = 0.f;
#pragma unroll
        for (int r = 0; r < 8; ++r) t += psum[r][threadIdx.x];
        pool[(size_t)blockIdx.x * NDIM + threadIdx.x] = t;
    }
}

// ---------------- final mean + layer-2 matvec ------------------------------
__global__ void mean_kernel(const float* __restrict__ pool,
                            const float* __restrict__ W2,
                            const float* __restrict__ b2,
                            float* __restrict__ out, int nb, float invn) {
    __shared__ float sm[4][NDIM];
    __shared__ float zs[NDIM];
    int lane = threadIdx.x & 63, wid = threadIdx.x >> 6;
    int row = blockIdx.x * 4 + wid;
    int stride = gridDim.x * 4;
    float s = 0.f;
    for (int i = row; i < nb; i += stride) s += pool[(long)i * NDIM + lane];
    sm[wid][lane] = s;
    __syncthreads();
    if (wid == 0) {
        zs[lane] = sm[0][lane] + sm[1][lane] + sm[2][lane] + sm[3][lane];
    }
    __syncthreads();
    if (wid == 0) {
        float y = 0.f;
#pragma unroll 8
        for (int j = 0; j < 64; ++j)
            y = fmaf(zs[j], W2[(size_t)j * 64 + lane], y);   // coalesced over lane
        atomicAdd(&out[lane], y * invn);
        if (blockIdx.x == 0) atomicAdd(&out[lane], b2[lane]);
    }
}

extern "C" void kernel_launch(void* const* d_in, const int* in_sizes, int n_in,
                              void* d_out, int out_size, void* d_ws, size_t ws_size,
                              hipStream_t stream) {
    const float* x      = (const float*)d_in[0];
    const int*   eidx   = (const int*)d_in[1];
    const float* W1     = (const float*)d_in[2];
    const float* a_src1 = (const float*)d_in[3];
    const float* a_dst1 = (const float*)d_in[4];
    const float* b1     = (const float*)d_in[5];
    const float* W2     = (const float*)d_in[6];
    const float* a_src2 = (const float*)d_in[7];
    const float* a_dst2 = (const float*)d_in[8];
    const float* b2     = (const float*)d_in[9];
    float* out = (float*)d_out;

    const int N = in_sizes[0] / 20;      // 100000 (< 2^17, required by u32 part pack)
    const int E = in_sizes[1] / 2;       // 1000000
    const int* src = eidx;
    const int* dst = eidx + E;
    const int NB = (N + BNODES - 1) >> BSHIFT;   // 391

    const int gemm_blocks = (N + 63) / 64;    // 1563 (64 nodes/block)
    const int agg_blocks  = (N + 7) / 8;      // 12500 (8 nodes/block, 2/wave)
    const int PB = (E + 2047) / 2048;         // 489 partition blocks

    // workspace layout
    char* ws = (char*)d_ws;
    unsigned char* h  = (unsigned char*)ws;           // N*64 fp8 (6.4 MB) layer-1
    unsigned char* o8 = h + (size_t)N * NDIM;         // N*64 fp8 (6.4 MB) layer-1 out
    float* as1  = (float*)(o8 + (size_t)N * NDIM);    // N
    float* ad1  = as1 + N;                            // N
    float* as2  = ad1 + N;                            // N
    float* ad2  = as2 + N;                            // N
    int2*  offlen = (int2*)(ad2 + N);                 // N
    int*   csr  = (int*)(offlen + N);                 // NB*CCAP
    float* pool = (float*)(csr + (size_t)NB * CCAP);  // agg_blocks*64
    float* atil = pool + (size_t)agg_blocks * NDIM;   // 128 (16B-aligned)
    int*   bcur = (int*)(atil + 128);                 // NB
    unsigned* part = (unsigned*)(bcur + NB);          // NB*ECAP u32 (5.6 MB)

    // stream-head memsets: out accumulator + 0-based bucket cursors
    hipMemsetAsync(d_out, 0, (size_t)out_size * sizeof(float), stream);
    hipMemsetAsync(bcur, 0, (size_t)NB * sizeof(int), stream);

    // partition + layer-1 GEMM (fused dispatch)
    pg_kernel<<<PB + gemm_blocks, 256, 0, stream>>>(
        src, dst, bcur, part, E, NB, PB,
        x, W1, a_src1, a_dst1, h, as1, ad1, N);
    // per-bucket CSR build (+ atil precompute)
    csr_kernel<<<NB, 256, 0, stream>>>(bcur, part, csr, offlen, N,
                                       W2, a_src2, a_dst2, atil);

    // layer-1 aggregation (writes fp8 o, as2, ad2)
    agg1_kernel<<<agg_blocks, 256, 0, stream>>>(
        offlen, csr, as1, ad1, h, b1, atil, o8, as2, ad2, N);

    // layer-2 aggregation in o-space (writes pool partials of z)
    agg2_kernel<<<agg_blocks, 256, 0, stream>>>(
        offlen, csr, as2, ad2, o8, pool, N);

    // final mean + W2 matvec + b2
    mean_kernel<<<64, 256, 0, stream>>>(pool, W2, b2, out, agg_blocks,
                                        1.0f / (float)N);
}